// Round 1
// baseline (561.241 us; speedup 1.0000x reference)
//
#include <hip/hip_runtime.h>
#include <math.h>

#define NPTS 20000
#define KNB  32
#define DDIM 64
#define HIDN 64
#define OUTC 192
#define PPB  4
#define HS   68   // LDS row stride for h (16B aligned, conflict-free for row-group reads)

__device__ __forceinline__ float dot4(float4 a, float4 b) {
  return a.x*b.x + a.y*b.y + a.z*b.z + a.w*b.w;
}

__device__ __forceinline__ float angle3(float ax, float ay, float az,
                                        float bx, float by, float bz) {
  const float y  = ax*bx + ay*by + az*bz;
  const float cx = ay*bz - az*by;
  const float cy = az*bx - ax*bz;
  const float cz = ax*by - ay*bx;
  const float xn = sqrtf(cx*cx + cy*cy + cz*cz);
  float xs;
  if (fabsf(y) < 1e-8f) {
    // jnp.sign(0) == 0 -> xs stays 0
    xs = (y > 0.f) ? 1e-8f : ((y < 0.f) ? -1e-8f : 0.f);
  } else {
    xs = y;
  }
  return atan2f(xn, xs) * 0.3183098861837907f; // 1/pi
}

__global__ __launch_bounds__(256, 2)
void ppf_fused(const float* __restrict__ q_pts,
               const float* __restrict__ s_pts,
               const float* __restrict__ s_feats,
               const int*   __restrict__ nbr,
               const float* __restrict__ normals,
               const float* __restrict__ W1, const float* __restrict__ b1,
               const float* __restrict__ W2, const float* __restrict__ b2,
               const float* __restrict__ W3, const float* __restrict__ b3,
               const float* __restrict__ Wg, const float* __restrict__ bg,
               const float* __restrict__ Wv,
               float* __restrict__ out)
{
  __shared__ float s_h[PPB][KNB][HS];      // 34816 B : h1, then h2 in place
  __shared__ float s_ppf[PPB][KNB][4];     //  2048 B
  __shared__ int   s_idx[PPB][KNB];        //   512 B
  __shared__ float s_part[PPB][4][HIDN];   //  4096 B : layer-3 partial row sums
  __shared__ float s_mod[PPB][HIDN];       //  1024 B
  __shared__ float s_gate[PPB][OUTC];      //  3072 B
  __shared__ float s_agg[PPB][3][DDIM];    //  3072 B : transposed [t][d]

  const int tid  = threadIdx.x;
  const int g    = tid >> 6;     // wave id == local point id
  const int lane = tid & 63;
  const int p    = blockIdx.x * PPB + g;

  // ---------------- Phase 0: PPF features (lanes 0..31 of each wave) --------
  {
    const float qx = q_pts[p*3+0], qy = q_pts[p*3+1], qz = q_pts[p*3+2];
    const int   i0 = nbr[p*KNB];
    const float qnx = normals[i0*3+0], qny = normals[i0*3+1], qnz = normals[i0*3+2];
    if (lane < KNB) {
      const int mi = nbr[p*KNB + lane];
      s_idx[g][lane] = mi;
      const float px = s_pts[mi*3+0], py = s_pts[mi*3+1], pz = s_pts[mi*3+2];
      const float nx = normals[mi*3+0], ny = normals[mi*3+1], nz = normals[mi*3+2];
      const float vx = px - qx, vy = py - qy, vz = pz - qz;
      s_ppf[g][lane][0] = sqrtf(vx*vx + vy*vy + vz*vz);
      s_ppf[g][lane][1] = angle3(qnx,qny,qnz, vx,vy,vz);
      s_ppf[g][lane][2] = angle3(nx,ny,nz,    vx,vy,vz);
      s_ppf[g][lane][3] = angle3(qnx,qny,qnz, nx,ny,nz);
    }
  }
  __syncthreads();

  // ---------------- Layer 1: (32 x 4) @ (4 x 64), lane = output column ------
  {
    const float4 w1v = *(const float4*)&W1[lane*4];
    const float  b1v = b1[lane];
#pragma unroll
    for (int k = 0; k < KNB; ++k) {
      const float4 pf = *(const float4*)&s_ppf[g][k][0];
      s_h[g][k][lane] = fmaxf(b1v + dot4(pf, w1v), 0.f);
    }
  }
  __syncthreads();

  const int jc = lane & 15;   // 16 column groups of 4
  const int kc = lane >> 4;   // 4 row groups; rows kc, kc+4, ..., kc+28

  // ---------------- Layer 2: (32 x 64) @ (64 x 64) + ReLU, in-place ---------
  {
    float4 acc[8];
    const float4 b2v = *(const float4*)&b2[jc*4];
#pragma unroll
    for (int rr = 0; rr < 8; ++rr) acc[rr] = b2v;
#pragma unroll
    for (int ic = 0; ic < 16; ++ic) {
      const float4 w0 = *(const float4*)&W2[(jc*4+0)*HIDN + ic*4];
      const float4 w1 = *(const float4*)&W2[(jc*4+1)*HIDN + ic*4];
      const float4 w2 = *(const float4*)&W2[(jc*4+2)*HIDN + ic*4];
      const float4 w3 = *(const float4*)&W2[(jc*4+3)*HIDN + ic*4];
#pragma unroll
      for (int rr = 0; rr < 8; ++rr) {
        const float4 h4 = *(const float4*)&s_h[g][kc + 4*rr][ic*4];
        acc[rr].x += dot4(h4, w0);
        acc[rr].y += dot4(h4, w1);
        acc[rr].z += dot4(h4, w2);
        acc[rr].w += dot4(h4, w3);
      }
    }
    __syncthreads();   // all reads of h1 done before overwriting with h2
#pragma unroll
    for (int rr = 0; rr < 8; ++rr) {
      float4 v;
      v.x = fmaxf(acc[rr].x, 0.f); v.y = fmaxf(acc[rr].y, 0.f);
      v.z = fmaxf(acc[rr].z, 0.f); v.w = fmaxf(acc[rr].w, 0.f);
      *(float4*)&s_h[g][kc + 4*rr][jc*4] = v;
    }
  }
  __syncthreads();

  // ---------------- Layer 3: (32 x 64) @ (64 x 64), fused mean over K -------
  {
    float4 acc[8];
    const float4 b3v = *(const float4*)&b3[jc*4];
#pragma unroll
    for (int rr = 0; rr < 8; ++rr) acc[rr] = b3v;
#pragma unroll
    for (int ic = 0; ic < 16; ++ic) {
      const float4 w0 = *(const float4*)&W3[(jc*4+0)*HIDN + ic*4];
      const float4 w1 = *(const float4*)&W3[(jc*4+1)*HIDN + ic*4];
      const float4 w2 = *(const float4*)&W3[(jc*4+2)*HIDN + ic*4];
      const float4 w3 = *(const float4*)&W3[(jc*4+3)*HIDN + ic*4];
#pragma unroll
      for (int rr = 0; rr < 8; ++rr) {
        const float4 h4 = *(const float4*)&s_h[g][kc + 4*rr][ic*4];
        acc[rr].x += dot4(h4, w0);
        acc[rr].y += dot4(h4, w1);
        acc[rr].z += dot4(h4, w2);
        acc[rr].w += dot4(h4, w3);
      }
    }
    float4 part = acc[0];
#pragma unroll
    for (int rr = 1; rr < 8; ++rr) {
      part.x += acc[rr].x; part.y += acc[rr].y;
      part.z += acc[rr].z; part.w += acc[rr].w;
    }
    *(float4*)&s_part[g][kc][jc*4] = part;
  }

  // ---------------- Neighbor-feature mean (per wave, overlaps nicely) -------
  {
#pragma unroll
    for (int it = 0; it < 3; ++it) {
      const int e = lane + 64*it;          // e = d*3 + t
      float s = 0.f;
#pragma unroll
      for (int k = 0; k < KNB; ++k) {
        s += s_feats[(size_t)s_idx[g][k]*(DDIM*3) + e];
      }
      s_agg[g][e % 3][e / 3] = s * (1.f/KNB);   // transposed [t][d]
    }
  }
  __syncthreads();

  // ---------------- ppf_mod = mean over K ----------------------------------
  {
    const float m = (s_part[g][0][lane] + s_part[g][1][lane] +
                     s_part[g][2][lane] + s_part[g][3][lane]) * (1.f/KNB);
    s_mod[g][lane] = m;
  }
  __syncthreads();

  // ---------------- Gate: sigmoid(ppf_mod @ Wg^T + bg), block-cooperative ---
  if (tid < OUTC) {
    const int o = tid;
    float a0 = bg[o], a1 = a0, a2 = a0, a3 = a0;
#pragma unroll
    for (int ic = 0; ic < 16; ++ic) {
      const float4 wg4 = *(const float4*)&Wg[o*HIDN + ic*4];
      a0 += dot4(*(const float4*)&s_mod[0][ic*4], wg4);
      a1 += dot4(*(const float4*)&s_mod[1][ic*4], wg4);
      a2 += dot4(*(const float4*)&s_mod[2][ic*4], wg4);
      a3 += dot4(*(const float4*)&s_mod[3][ic*4], wg4);
    }
    s_gate[0][o] = 1.f/(1.f + expf(-a0));
    s_gate[1][o] = 1.f/(1.f + expf(-a1));
    s_gate[2][o] = 1.f/(1.f + expf(-a2));
    s_gate[3][o] = 1.f/(1.f + expf(-a3));
  }
  __syncthreads();

  // ---------------- Transform + gating + store, block-cooperative -----------
  if (tid < OUTC) {
    const int o = tid;
    float acct[PPB][3];
#pragma unroll
    for (int gg = 0; gg < PPB; ++gg)
#pragma unroll
      for (int tt = 0; tt < 3; ++tt) acct[gg][tt] = 0.f;

#pragma unroll
    for (int ic = 0; ic < 16; ++ic) {
      const float4 wv4 = *(const float4*)&Wv[o*DDIM + ic*4];
#pragma unroll
      for (int gg = 0; gg < PPB; ++gg) {
#pragma unroll
        for (int tt = 0; tt < 3; ++tt) {
          const float4 a4 = *(const float4*)&s_agg[gg][tt][ic*4];
          acct[gg][tt] += dot4(wv4, a4);
        }
      }
    }
    const int pbase = blockIdx.x * PPB;
#pragma unroll
    for (int gg = 0; gg < PPB; ++gg) {
      const float gt = s_gate[gg][o];
#pragma unroll
      for (int tt = 0; tt < 3; ++tt) {
        out[(size_t)(pbase + gg)*(OUTC*3) + o*3 + tt] = acct[gg][tt] * gt;
      }
    }
  }
}

extern "C" void kernel_launch(void* const* d_in, const int* in_sizes, int n_in,
                              void* d_out, int out_size, void* d_ws, size_t ws_size,
                              hipStream_t stream) {
  const float* q_pts   = (const float*)d_in[0];
  const float* s_pts   = (const float*)d_in[1];
  const float* s_feats = (const float*)d_in[2];
  const int*   nbr     = (const int*)  d_in[3];
  const float* normals = (const float*)d_in[4];
  const float* W1 = (const float*)d_in[5];
  const float* b1 = (const float*)d_in[6];
  const float* W2 = (const float*)d_in[7];
  const float* b2 = (const float*)d_in[8];
  const float* W3 = (const float*)d_in[9];
  const float* b3 = (const float*)d_in[10];
  const float* Wg = (const float*)d_in[11];
  const float* bg = (const float*)d_in[12];
  const float* Wv = (const float*)d_in[13];
  float* out = (float*)d_out;

  dim3 grid(NPTS / PPB);
  dim3 block(256);
  hipLaunchKernelGGL(ppf_fused, grid, block, 0, stream,
                     q_pts, s_pts, s_feats, nbr, normals,
                     W1, b1, W2, b2, W3, b3, Wg, bg, Wv, out);
}

// Round 2
// 233.131 us; speedup vs baseline: 2.4074x; 2.4074x over previous
//
#include <hip/hip_runtime.h>
#include <math.h>

#define NPTS 20000
#define KNB  32
#define DDIM 64
#define HIDN 64
#define OUTC 192
#define PPB  4

// MFMA fragment types per cdna_hip_programming.md §3 (gfx950, 16x16x32 bf16)
typedef short bf16x8 __attribute__((ext_vector_type(8)));   // 8 bf16 in 4 VGPRs
typedef float f32x4  __attribute__((ext_vector_type(4)));   // 4 fp32 acc

union BF8 { bf16x8 v; unsigned short us[8]; unsigned u[4]; };

__device__ __forceinline__ unsigned short f2bfu(float f) {  // fp32 -> bf16 bits, RNE
  unsigned u = __builtin_bit_cast(unsigned, f);
  u += 0x7fffu + ((u >> 16) & 1u);
  return (unsigned short)(u >> 16);
}

__device__ __forceinline__ float angle3(float ax, float ay, float az,
                                        float bx, float by, float bz) {
  const float y  = ax*bx + ay*by + az*bz;
  const float cx = ay*bz - az*by;
  const float cy = az*bx - ax*bz;
  const float cz = ax*by - ay*bx;
  const float xn = sqrtf(cx*cx + cy*cy + cz*cz);
  float xs;
  if (fabsf(y) < 1e-8f) {
    xs = (y > 0.f) ? 1e-8f : ((y < 0.f) ? -1e-8f : 0.f);  // sign(0)=0
  } else {
    xs = y;
  }
  return atan2f(xn, xs) * 0.3183098861837907f; // 1/pi
}

__device__ __forceinline__ float dot4(float4 a, float4 b) {
  return a.x*b.x + a.y*b.y + a.z*b.z + a.w*b.w;
}

__global__ __launch_bounds__(256, 3)
void ppf_fused(const float* __restrict__ q_pts,
               const float* __restrict__ s_pts,
               const float* __restrict__ s_feats,
               const int*   __restrict__ nbr,
               const float* __restrict__ normals,
               const float* __restrict__ W1, const float* __restrict__ b1,
               const float* __restrict__ W2, const float* __restrict__ b2,
               const float* __restrict__ W3, const float* __restrict__ b3,
               const float* __restrict__ Wg, const float* __restrict__ bg,
               const float* __restrict__ Wv,
               float* __restrict__ out)
{
  // h tiles: bf16 bits, row-major [32 rows=neighbors][72 cols padded]; 144 B row
  // stride keeps ds_read_b128 A-frag reads 16B-aligned. Aliased as s_out later.
  __shared__ __align__(16) unsigned short s_h[PPB][KNB][72];  // 18432 B
  __shared__ __align__(16) unsigned short W2f[4096];          //  8192 B B-frag layout
  __shared__ __align__(16) unsigned short W3f[4096];          //  8192 B
  __shared__ float s_ppf[PPB][KNB][4];                        //  2048 B
  __shared__ int   s_idx[PPB][KNB];                           //   512 B
  __shared__ float s_mod[PPB][HIDN];                          //  1024 B
  __shared__ float s_gate[PPB][OUTC];                         //  3072 B
  __shared__ float s_agg[PPB][3][DDIM];                       //  3072 B
  float* s_out = (float*)&s_h[0][0][0];                       // alias, 9216 B used

  const int tid  = threadIdx.x;
  const int g    = tid >> 6;
  const int lane = tid & 63;
  const int p    = blockIdx.x * PPB + g;
  const int lq   = lane >> 4;     // quad group
  const int ln   = lane & 15;

  // ---- Stage W2/W3 into bf16 B-fragment layout (lane-major, conflict-free) --
  // frag(ct,ks): element j of lane L = W[n][k], n=(L&15)+16ct, k=(L>>4)*8+j+32ks
  for (int w = 0; w < 2; ++w) {
    const float* W = w ? W3 : W2;
    unsigned short* Wf = w ? W3f : W2f;
#pragma unroll
    for (int i = 0; i < 4; ++i) {
      const int e0 = tid*16 + i*4;            // covers [0,4096) in float4s
      const float4 x = *(const float4*)&W[e0];
      const int m  = e0 >> 6, k0 = e0 & 63;
      const int fr = (m >> 4)*2 + (k0 >> 5);
      const int lm = ((k0 >> 3) & 3)*16 + (m & 15);
      const int di = fr*512 + lm*8 + (k0 & 7);   // ushort units, %4==0 -> 8B aligned
      unsigned lo = f2bfu(x.x) | ((unsigned)f2bfu(x.y) << 16);
      unsigned hi = f2bfu(x.z) | ((unsigned)f2bfu(x.w) << 16);
      *(uint2*)&Wf[di] = make_uint2(lo, hi);
    }
  }

  // ---- Phase A: PPF features (lanes 0..31 of each wave) ---------------------
  {
    const float qx = q_pts[p*3+0], qy = q_pts[p*3+1], qz = q_pts[p*3+2];
    const int   i0 = nbr[p*KNB];
    const float qnx = normals[i0*3+0], qny = normals[i0*3+1], qnz = normals[i0*3+2];
    if (lane < KNB) {
      const int mi = nbr[p*KNB + lane];
      s_idx[g][lane] = mi;
      const float px = s_pts[mi*3+0], py = s_pts[mi*3+1], pz = s_pts[mi*3+2];
      const float nx = normals[mi*3+0], ny = normals[mi*3+1], nz = normals[mi*3+2];
      const float vx = px - qx, vy = py - qy, vz = pz - qz;
      s_ppf[g][lane][0] = sqrtf(vx*vx + vy*vy + vz*vz);
      s_ppf[g][lane][1] = angle3(qnx,qny,qnz, vx,vy,vz);
      s_ppf[g][lane][2] = angle3(nx,ny,nz,    vx,vy,vz);
      s_ppf[g][lane][3] = angle3(qnx,qny,qnz, nx,ny,nz);
    }
  }
  __syncthreads();   // Wf visible to all waves (s_ppf/s_idx are wave-private)

  // ---- Layer 1 via MFMA: h1 = relu(ppf(32x4,pad32) @ W1^T + b1) -------------
  {
    BF8 a1[2];
    a1[0].u[0]=a1[0].u[1]=a1[0].u[2]=a1[0].u[3]=0;
    a1[1] = a1[0];
    if (lq == 0) {
#pragma unroll
      for (int rt = 0; rt < 2; ++rt) {
        const float4 pv = *(const float4*)&s_ppf[g][ln + 16*rt][0];
        a1[rt].us[0]=f2bfu(pv.x); a1[rt].us[1]=f2bfu(pv.y);
        a1[rt].us[2]=f2bfu(pv.z); a1[rt].us[3]=f2bfu(pv.w);
      }
    }
#pragma unroll
    for (int ct = 0; ct < 4; ++ct) {
      BF8 bw; bw.u[0]=bw.u[1]=bw.u[2]=bw.u[3]=0;
      if (lq == 0) {
        const float4 wv = *(const float4*)&W1[(ln + 16*ct)*4];
        bw.us[0]=f2bfu(wv.x); bw.us[1]=f2bfu(wv.y);
        bw.us[2]=f2bfu(wv.z); bw.us[3]=f2bfu(wv.w);
      }
      const float bv = b1[ln + 16*ct];
#pragma unroll
      for (int rt = 0; rt < 2; ++rt) {
        f32x4 c = {bv, bv, bv, bv};
        c = __builtin_amdgcn_mfma_f32_16x16x32_bf16(a1[rt].v, bw.v, c, 0, 0, 0);
#pragma unroll
        for (int r = 0; r < 4; ++r)  // C: col=ln+16ct, row=lq*4+r+16rt
          s_h[g][lq*4 + r + 16*rt][ln + 16*ct] = f2bfu(fmaxf(c[r], 0.f));
      }
    }
  }

  // ---- Layer 2 via MFMA: h2 = relu(h1 @ W2^T + b2), in place ----------------
  // (in-place safe: the wave's 4 A-frag ds_reads precede all ds_writes in the
  //  instruction stream; per-wave LDS ops are processed in order)
  {
    bf16x8 a2[4];
#pragma unroll
    for (int rt = 0; rt < 2; ++rt)
#pragma unroll
      for (int ks = 0; ks < 2; ++ks)
        a2[rt*2+ks] = *(const bf16x8*)&s_h[g][ln + 16*rt][lq*8 + ks*32];
#pragma unroll
    for (int ct = 0; ct < 4; ++ct) {
      const bf16x8 bf0 = *(const bf16x8*)&W2f[(ct*2+0)*512 + lane*8];
      const bf16x8 bf1 = *(const bf16x8*)&W2f[(ct*2+1)*512 + lane*8];
      const float bv = b2[ln + 16*ct];
#pragma unroll
      for (int rt = 0; rt < 2; ++rt) {
        f32x4 c = {bv, bv, bv, bv};
        c = __builtin_amdgcn_mfma_f32_16x16x32_bf16(a2[rt*2+0], bf0, c, 0, 0, 0);
        c = __builtin_amdgcn_mfma_f32_16x16x32_bf16(a2[rt*2+1], bf1, c, 0, 0, 0);
#pragma unroll
        for (int r = 0; r < 4; ++r)
          s_h[g][lq*4 + r + 16*rt][ln + 16*ct] = f2bfu(fmaxf(c[r], 0.f));
      }
    }
  }

  // ---- Layer 3 via MFMA + fused mean over K (rows) --------------------------
  {
    bf16x8 a3[4];
#pragma unroll
    for (int rt = 0; rt < 2; ++rt)
#pragma unroll
      for (int ks = 0; ks < 2; ++ks)
        a3[rt*2+ks] = *(const bf16x8*)&s_h[g][ln + 16*rt][lq*8 + ks*32];
#pragma unroll
    for (int ct = 0; ct < 4; ++ct) {
      const bf16x8 bf0 = *(const bf16x8*)&W3f[(ct*2+0)*512 + lane*8];
      const bf16x8 bf1 = *(const bf16x8*)&W3f[(ct*2+1)*512 + lane*8];
      const float bv = b3[ln + 16*ct];
      f32x4 c0 = {bv, bv, bv, bv};
      c0 = __builtin_amdgcn_mfma_f32_16x16x32_bf16(a3[0], bf0, c0, 0, 0, 0);
      c0 = __builtin_amdgcn_mfma_f32_16x16x32_bf16(a3[1], bf1, c0, 0, 0, 0);
      f32x4 c1 = {bv, bv, bv, bv};
      c1 = __builtin_amdgcn_mfma_f32_16x16x32_bf16(a3[2], bf0, c1, 0, 0, 0);
      c1 = __builtin_amdgcn_mfma_f32_16x16x32_bf16(a3[3], bf1, c1, 0, 0, 0);
      // rows per lane-reg: lq*4+r (+16rt) -> in-lane sum + butterfly over quads
      float s = (c0[0]+c0[1]+c0[2]+c0[3]) + (c1[0]+c1[1]+c1[2]+c1[3]);
      s += __shfl_xor(s, 16);
      s += __shfl_xor(s, 32);
      if (lq == 0) s_mod[g][ln + 16*ct] = s * (1.f/KNB);
    }
  }

  // ---- Neighbor-feature mean: one dwordx3 per row per lane ------------------
  {
    float s0 = 0.f, s1 = 0.f, s2 = 0.f;
#pragma unroll
    for (int k = 0; k < KNB; ++k) {
      const float* fr = s_feats + (size_t)s_idx[g][k]*(DDIM*3) + lane*3;
      s0 += fr[0]; s1 += fr[1]; s2 += fr[2];
    }
    // element lane*3+c = (d=lane, t=c); store transposed [t][d]
    s_agg[g][0][lane] = s0 * (1.f/KNB);
    s_agg[g][1][lane] = s1 * (1.f/KNB);
    s_agg[g][2][lane] = s2 * (1.f/KNB);
  }
  __syncthreads();

  // ---- Gate: sigmoid(ppf_mod @ Wg^T + bg), block-cooperative ----------------
  if (tid < OUTC) {
    const int o = tid;
    float a0 = bg[o], a1 = a0, a2 = a0, a3 = a0;
#pragma unroll
    for (int ic = 0; ic < 16; ++ic) {
      const float4 wg4 = *(const float4*)&Wg[o*HIDN + ic*4];
      a0 += dot4(*(const float4*)&s_mod[0][ic*4], wg4);
      a1 += dot4(*(const float4*)&s_mod[1][ic*4], wg4);
      a2 += dot4(*(const float4*)&s_mod[2][ic*4], wg4);
      a3 += dot4(*(const float4*)&s_mod[3][ic*4], wg4);
    }
    s_gate[0][o] = 1.f/(1.f + expf(-a0));
    s_gate[1][o] = 1.f/(1.f + expf(-a1));
    s_gate[2][o] = 1.f/(1.f + expf(-a2));
    s_gate[3][o] = 1.f/(1.f + expf(-a3));
  }
  __syncthreads();   // also: all layer-3 reads of s_h done -> s_out alias safe

  // ---- Transform + gating -> stage to LDS ----------------------------------
  if (tid < OUTC) {
    const int o = tid;
    float acct[PPB][3];
#pragma unroll
    for (int gg = 0; gg < PPB; ++gg)
#pragma unroll
      for (int tt = 0; tt < 3; ++tt) acct[gg][tt] = 0.f;
#pragma unroll
    for (int ic = 0; ic < 16; ++ic) {
      const float4 wv4 = *(const float4*)&Wv[o*DDIM + ic*4];
#pragma unroll
      for (int gg = 0; gg < PPB; ++gg) {
#pragma unroll
        for (int tt = 0; tt < 3; ++tt)
          acct[gg][tt] += dot4(wv4, *(const float4*)&s_agg[gg][tt][ic*4]);
      }
    }
#pragma unroll
    for (int gg = 0; gg < PPB; ++gg) {
      const float gt = s_gate[gg][o];
#pragma unroll
      for (int tt = 0; tt < 3; ++tt)
        s_out[gg*(OUTC*3) + o*3 + tt] = acct[gg][tt] * gt;
    }
  }
  __syncthreads();

  // ---- Coalesced float4 output write (full cache lines) ---------------------
  {
    float4* outv = (float4*)out;
    const float4* sov = (const float4*)s_out;
#pragma unroll
    for (int i = 0; i < 3; ++i) {
      const int idx = tid + 256*i;
      if (idx < (PPB*OUTC*3)/4)
        outv[(size_t)blockIdx.x * ((PPB*OUTC*3)/4) + idx] = sov[idx];
    }
  }
}

extern "C" void kernel_launch(void* const* d_in, const int* in_sizes, int n_in,
                              void* d_out, int out_size, void* d_ws, size_t ws_size,
                              hipStream_t stream) {
  const float* q_pts   = (const float*)d_in[0];
  const float* s_pts   = (const float*)d_in[1];
  const float* s_feats = (const float*)d_in[2];
  const int*   nbr     = (const int*)  d_in[3];
  const float* normals = (const float*)d_in[4];
  const float* W1 = (const float*)d_in[5];
  const float* b1 = (const float*)d_in[6];
  const float* W2 = (const float*)d_in[7];
  const float* b2 = (const float*)d_in[8];
  const float* W3 = (const float*)d_in[9];
  const float* b3 = (const float*)d_in[10];
  const float* Wg = (const float*)d_in[11];
  const float* bg = (const float*)d_in[12];
  const float* Wv = (const float*)d_in[13];
  float* out = (float*)d_out;

  dim3 grid(NPTS / PPB);
  dim3 block(256);
  hipLaunchKernelGGL(ppf_fused, grid, block, 0, stream,
                     q_pts, s_pts, s_feats, nbr, normals,
                     W1, b1, W2, b2, W3, b3, Wg, bg, Wv, out);
}

// Round 3
// 171.404 us; speedup vs baseline: 3.2744x; 1.3601x over previous
//
#include <hip/hip_runtime.h>
#include <hip/hip_bf16.h>
#include <math.h>

#define NPTS 20000
#define KNB  32
#define DDIM 64
#define HIDN 64
#define OUTC 192
#define PPB  4

// d_ws layout, ushort units (bf16 MFMA fragments, 512 ushorts = 1 frag)
#define WS_W2 0        // 8 frags  (ct*2+ks)
#define WS_W3 4096     // 8 frags
#define WS_W1 8192     // 4 frags  (ct)
#define WS_WG 10240    // 24 frags (ot*2+ks)
#define WS_WV 22528    // 24 frags (ot*2+ks)
// total 69632 bytes

typedef short bf16x8 __attribute__((ext_vector_type(8)));
typedef float f32x4  __attribute__((ext_vector_type(4)));

union BF8 { bf16x8 v; unsigned short us[8]; unsigned u[4]; };

__device__ __forceinline__ unsigned short f2bf(float f) {
  return __builtin_bit_cast(unsigned short, __float2bfloat16(f));
}

__device__ __forceinline__ float fast_atan2pi(float y, float x) {
  // y >= 0; returns atan2(y,x)/pi; abs err ~1e-6 (minimax deg-11 + v_rcp)
  const float ax = fabsf(x);
  const float mx = fmaxf(fmaxf(ax, y), 1e-30f);
  const float mn = fminf(ax, y);
  const float t  = mn * __builtin_amdgcn_rcpf(mx);
  const float s  = t * t;
  float p = -0.0117212f;
  p = fmaf(p, s,  0.05265332f);
  p = fmaf(p, s, -0.11643287f);
  p = fmaf(p, s,  0.19354346f);
  p = fmaf(p, s, -0.33262347f);
  p = fmaf(p, s,  0.99997726f);
  float r = p * t;
  if (y > ax)  r = 1.5707963268f - r;
  if (x < 0.f) r = 3.1415926536f - r;
  return r * 0.3183098862f;
}

__device__ __forceinline__ float angle3f(float ax, float ay, float az,
                                         float bx, float by, float bz) {
  const float y  = ax*bx + ay*by + az*bz;
  const float cx = ay*bz - az*by;
  const float cy = az*bx - ax*bz;
  const float cz = ax*by - ay*bx;
  const float xn = __builtin_amdgcn_sqrtf(cx*cx + cy*cy + cz*cz);
  return fast_atan2pi(xn, y);   // matches ref eps-semantics within tolerance
}

// ---- prep: convert weights to bf16 fragment layout in d_ws ------------------
// frag element j of lane L = M[(L&15)+16*ct][(L>>4)*8 + j + 32*ks]
__global__ void prep_weights(const float* __restrict__ W1, const float* __restrict__ W2,
                             const float* __restrict__ W3, const float* __restrict__ Wg,
                             const float* __restrict__ Wv, unsigned short* __restrict__ ws)
{
  const int f  = blockIdx.x;     // 68 frags
  const int L  = threadIdx.x;    // 64 lanes
  const int ln = L & 15, lq = L >> 4;
  unsigned short vals[8];
  if (f >= 16 && f < 20) {       // W1 [64][4], K padded to 32
    const int ct = f - 16;
#pragma unroll
    for (int j = 0; j < 8; ++j) {
      const float v = (lq == 0 && j < 4) ? W1[(ln + 16*ct)*4 + j] : 0.f;
      vals[j] = f2bf(v);
    }
  } else {
    const float* M; int q;
    if (f < 8)       { M = W2; q = f; }
    else if (f < 16) { M = W3; q = f - 8; }
    else if (f < 44) { M = Wg; q = f - 20; }
    else             { M = Wv; q = f - 44; }
    const int ct = q >> 1, ks = q & 1;
    const float* src = M + (ln + 16*ct)*64 + lq*8 + 32*ks;
#pragma unroll
    for (int j = 0; j < 8; ++j) vals[j] = f2bf(src[j]);
  }
  uint4 w;
  w.x = vals[0] | ((unsigned)vals[1] << 16);
  w.y = vals[2] | ((unsigned)vals[3] << 16);
  w.z = vals[4] | ((unsigned)vals[5] << 16);
  w.w = vals[6] | ((unsigned)vals[7] << 16);
  *(uint4*)&ws[f*512 + L*8] = w;
}

// ---- main fused kernel ------------------------------------------------------
__global__ __launch_bounds__(256, 4)
void ppf_fused(const float* __restrict__ q_pts,
               const float* __restrict__ s_pts,
               const float* __restrict__ s_feats,
               const int*   __restrict__ nbr,
               const float* __restrict__ normals,
               const float* __restrict__ b1, const float* __restrict__ b2,
               const float* __restrict__ b3, const float* __restrict__ bg,
               const unsigned short* __restrict__ wsu,
               float* __restrict__ out)
{
  __shared__ __align__(16) unsigned short s_h[PPB][KNB][72];   // 18432 B (alias s_out)
  __shared__ __align__(16) float s_ppf[PPB][KNB][4];           //  2048 B
  __shared__ __align__(16) unsigned short s_modb[16][72];      //  2304 B rows=points(pad)
  __shared__ __align__(16) unsigned short s_aggb[16][72];      //  2304 B rows=(g,t)(pad)
  __shared__ float s_gate[PPB][200];                           //  3200 B (padded)
  float* s_out = (float*)&s_h[0][0][0];                        // 4 x 592 floats

  const int tid  = threadIdx.x;
  const int g    = tid >> 6;
  const int lane = tid & 63;
  const int lq   = lane >> 4;
  const int ln   = lane & 15;
  const int pu   = __builtin_amdgcn_readfirstlane(blockIdx.x * PPB + g);

  // ---- Phase A: PPF features, split across wave halves ----------------------
  {
    const float qx = q_pts[pu*3+0], qy = q_pts[pu*3+1], qz = q_pts[pu*3+2];
    const int   i0 = nbr[pu*KNB];
    const float qnx = normals[i0*3+0], qny = normals[i0*3+1], qnz = normals[i0*3+2];
    const int k  = lane & 31;
    const int mi = nbr[pu*KNB + k];
    const float px = s_pts[mi*3+0], py = s_pts[mi*3+1], pz = s_pts[mi*3+2];
    const float nx = normals[mi*3+0], ny = normals[mi*3+1], nz = normals[mi*3+2];
    const float vx = px - qx, vy = py - qy, vz = pz - qz;
    if (lane < KNB) {
      s_ppf[g][k][1] = angle3f(qnx,qny,qnz, vx,vy,vz);
      s_ppf[g][k][2] = angle3f(nx,ny,nz,    vx,vy,vz);
    } else {
      s_ppf[g][k][0] = __builtin_amdgcn_sqrtf(vx*vx + vy*vy + vz*vz);
      s_ppf[g][k][3] = angle3f(qnx,qny,qnz, nx,ny,nz);
    }
  }
  // s_ppf produced and consumed by the same wave; DS ops are in-order per wave.

  // ---- Layer 1: h1 = relu(ppf @ W1^T + b1) via MFMA -------------------------
  {
    BF8 a1[2];
    a1[0].u[0]=a1[0].u[1]=a1[0].u[2]=a1[0].u[3]=0;
    a1[1] = a1[0];
    if (lq == 0) {
#pragma unroll
      for (int rt = 0; rt < 2; ++rt) {
        const float4 pv = *(const float4*)&s_ppf[g][ln + 16*rt][0];
        a1[rt].us[0]=f2bf(pv.x); a1[rt].us[1]=f2bf(pv.y);
        a1[rt].us[2]=f2bf(pv.z); a1[rt].us[3]=f2bf(pv.w);
      }
    }
#pragma unroll
    for (int ct = 0; ct < 4; ++ct) {
      const bf16x8 bw = *(const bf16x8*)&wsu[WS_W1 + ct*512 + lane*8];
      const float  bv = b1[ln + 16*ct];
#pragma unroll
      for (int rt = 0; rt < 2; ++rt) {
        f32x4 c = {bv, bv, bv, bv};
        c = __builtin_amdgcn_mfma_f32_16x16x32_bf16(a1[rt].v, bw, c, 0, 0, 0);
#pragma unroll
        for (int r = 0; r < 4; ++r)
          s_h[g][lq*4 + r + 16*rt][ln + 16*ct] = f2bf(fmaxf(c[r], 0.f));
      }
    }
  }

  // ---- Layer 2: h2 = relu(h1 @ W2^T + b2), in place -------------------------
  {
    bf16x8 wf[8];
#pragma unroll
    for (int fIdx = 0; fIdx < 8; ++fIdx)
      wf[fIdx] = *(const bf16x8*)&wsu[WS_W2 + fIdx*512 + lane*8];
    bf16x8 a2[4];
#pragma unroll
    for (int rt = 0; rt < 2; ++rt)
#pragma unroll
      for (int ks = 0; ks < 2; ++ks)
        a2[rt*2+ks] = *(const bf16x8*)&s_h[g][ln + 16*rt][lq*8 + ks*32];
#pragma unroll
    for (int ct = 0; ct < 4; ++ct) {
      const float bv = b2[ln + 16*ct];
#pragma unroll
      for (int rt = 0; rt < 2; ++rt) {
        f32x4 c = {bv, bv, bv, bv};
        c = __builtin_amdgcn_mfma_f32_16x16x32_bf16(a2[rt*2+0], wf[ct*2+0], c, 0, 0, 0);
        c = __builtin_amdgcn_mfma_f32_16x16x32_bf16(a2[rt*2+1], wf[ct*2+1], c, 0, 0, 0);
#pragma unroll
        for (int r = 0; r < 4; ++r)
          s_h[g][lq*4 + r + 16*rt][ln + 16*ct] = f2bf(fmaxf(c[r], 0.f));
      }
    }
  }

  // ---- Layer 3 + fused mean over K -> s_modb (bf16, row = point) ------------
  {
    bf16x8 wf[8];
#pragma unroll
    for (int fIdx = 0; fIdx < 8; ++fIdx)
      wf[fIdx] = *(const bf16x8*)&wsu[WS_W3 + fIdx*512 + lane*8];
    bf16x8 a3[4];
#pragma unroll
    for (int rt = 0; rt < 2; ++rt)
#pragma unroll
      for (int ks = 0; ks < 2; ++ks)
        a3[rt*2+ks] = *(const bf16x8*)&s_h[g][ln + 16*rt][lq*8 + ks*32];
#pragma unroll
    for (int ct = 0; ct < 4; ++ct) {
      const float bv = b3[ln + 16*ct];
      f32x4 c0 = {bv, bv, bv, bv};
      c0 = __builtin_amdgcn_mfma_f32_16x16x32_bf16(a3[0], wf[ct*2+0], c0, 0, 0, 0);
      c0 = __builtin_amdgcn_mfma_f32_16x16x32_bf16(a3[1], wf[ct*2+1], c0, 0, 0, 0);
      f32x4 c1 = {bv, bv, bv, bv};
      c1 = __builtin_amdgcn_mfma_f32_16x16x32_bf16(a3[2], wf[ct*2+0], c1, 0, 0, 0);
      c1 = __builtin_amdgcn_mfma_f32_16x16x32_bf16(a3[3], wf[ct*2+1], c1, 0, 0, 0);
      float s = (c0[0]+c0[1]+c0[2]+c0[3]) + (c1[0]+c1[1]+c1[2]+c1[3]);
      s += __shfl_xor(s, 16);
      s += __shfl_xor(s, 32);
      if (lq == 0) s_modb[g][ln + 16*ct] = f2bf(s * (1.f/KNB));
    }
  }

  // ---- Neighbor-feature mean (scalar indices -> SGPR addressing) ------------
  {
    float s0 = 0.f, s1 = 0.f, s2 = 0.f;
    const int lofs = lane * 3;
#pragma unroll 8
    for (int k = 0; k < KNB; ++k) {
      const int mi = nbr[pu*KNB + k];                    // wave-uniform: s_load
      const float* fr = s_feats + (size_t)mi*(DDIM*3) + lofs;
      s0 += fr[0]; s1 += fr[1]; s2 += fr[2];
    }
    // s_aggb row n = g*3+t, col d = lane
    s_aggb[g*3+0][lane] = f2bf(s0 * (1.f/KNB));
    s_aggb[g*3+1][lane] = f2bf(s1 * (1.f/KNB));
    s_aggb[g*3+2][lane] = f2bf(s2 * (1.f/KNB));
  }
  __syncthreads();   // s_modb/s_aggb cross-wave; also all s_h reads drained

  // ---- Gate via MFMA: rows = points (4 valid), cols = 192 outputs -----------
  {
    const bf16x8 am0 = *(const bf16x8*)&s_modb[ln][lq*8];
    const bf16x8 am1 = *(const bf16x8*)&s_modb[ln][lq*8 + 32];
#pragma unroll
    for (int t = 0; t < 3; ++t) {
      const int ot = g*3 + t;                       // this wave's 3 col-tiles
      const bf16x8 bg0 = *(const bf16x8*)&wsu[WS_WG + (ot*2+0)*512 + lane*8];
      const bf16x8 bg1 = *(const bf16x8*)&wsu[WS_WG + (ot*2+1)*512 + lane*8];
      const float  bv  = bg[ln + 16*ot];
      f32x4 c = {bv, bv, bv, bv};
      c = __builtin_amdgcn_mfma_f32_16x16x32_bf16(am0, bg0, c, 0, 0, 0);
      c = __builtin_amdgcn_mfma_f32_16x16x32_bf16(am1, bg1, c, 0, 0, 0);
      if (lq == 0) {
#pragma unroll
        for (int r = 0; r < 4; ++r)   // row r = point r
          s_gate[r][ln + 16*ot] = 1.f / (1.f + __expf(-c[r]));
      }
    }
  }

  // ---- Transform via MFMA: rows = outputs, cols = (point,t) -----------------
  {
    const bf16x8 ab0 = *(const bf16x8*)&s_aggb[ln][lq*8];        // B[n=(g,t)][k=d]
    const bf16x8 ab1 = *(const bf16x8*)&s_aggb[ln][lq*8 + 32];
    const int gi = ln / 3;            // valid for ln < 12
    const int tt = ln - gi*3;
#pragma unroll
    for (int t2 = 0; t2 < 3; ++t2) {
      const int ot = g*3 + t2;                      // this wave's 3 row-tiles
      const bf16x8 av0 = *(const bf16x8*)&wsu[WS_WV + (ot*2+0)*512 + lane*8];
      const bf16x8 av1 = *(const bf16x8*)&wsu[WS_WV + (ot*2+1)*512 + lane*8];
      f32x4 c = {0.f, 0.f, 0.f, 0.f};
      c = __builtin_amdgcn_mfma_f32_16x16x32_bf16(av0, ab0, c, 0, 0, 0);
      c = __builtin_amdgcn_mfma_f32_16x16x32_bf16(av1, ab1, c, 0, 0, 0);
      if (ln < 12) {
#pragma unroll
        for (int r = 0; r < 4; ++r) {
          const int o = 16*ot + lq*4 + r;
          s_out[gi*592 + o*3 + tt] = c[r] * s_gate[gi][o];
        }
      }
    }
  }
  __syncthreads();

  // ---- Coalesced float4 output write ----------------------------------------
  {
    float4* outv = (float4*)out;
    const float4* sov = (const float4*)s_out;
#pragma unroll
    for (int i = 0; i < 3; ++i) {
      const int idx = tid + 256*i;
      if (idx < 576) {
        const int gg  = idx / 144;
        const int off = idx - gg*144;
        outv[(size_t)blockIdx.x * 576 + idx] = sov[gg*148 + off];
      }
    }
  }
}

extern "C" void kernel_launch(void* const* d_in, const int* in_sizes, int n_in,
                              void* d_out, int out_size, void* d_ws, size_t ws_size,
                              hipStream_t stream) {
  const float* q_pts   = (const float*)d_in[0];
  const float* s_pts   = (const float*)d_in[1];
  const float* s_feats = (const float*)d_in[2];
  const int*   nbr     = (const int*)  d_in[3];
  const float* normals = (const float*)d_in[4];
  const float* W1 = (const float*)d_in[5];
  const float* b1 = (const float*)d_in[6];
  const float* W2 = (const float*)d_in[7];
  const float* b2 = (const float*)d_in[8];
  const float* W3 = (const float*)d_in[9];
  const float* b3 = (const float*)d_in[10];
  const float* Wg = (const float*)d_in[11];
  const float* bg = (const float*)d_in[12];
  const float* Wv = (const float*)d_in[13];
  float* out = (float*)d_out;
  unsigned short* ws = (unsigned short*)d_ws;

  hipLaunchKernelGGL(prep_weights, dim3(68), dim3(64), 0, stream,
                     W1, W2, W3, Wg, Wv, ws);
  hipLaunchKernelGGL(ppf_fused, dim3(NPTS / PPB), dim3(256), 0, stream,
                     q_pts, s_pts, s_feats, nbr, normals,
                     b1, b2, b3, bg, ws, out);
}